// Round 2
// baseline (2731.276 us; speedup 1.0000x reference)
//
#include <hip/hip_runtime.h>
#include <cstdint>
#include <cstddef>

// MoNet (GMM graph conv) forward, MI355X.
// N=50000, E=800000, IN_DIM=128, HID=64, K=3, PDIM=2, NCLS=16, 3 hidden layers.
// Push-based edge scatter with f32 atomics; per-edge gauss precomputed per layer;
// fp32 GEMMs with LDS-staged weights (no fp32 MFMA on CDNA4).
// Edge kernel vectorized: float4 gather, 4 channels/lane.

#define EPS 1e-5f

// ---------------- degree + pseudo ----------------
__global__ void degree_kernel(const int* __restrict__ rowi, const int* __restrict__ coli,
                              int* __restrict__ dr, int* __restrict__ dc, int E) {
    int i = blockIdx.x * blockDim.x + threadIdx.x;
    int stride = gridDim.x * blockDim.x;
    for (; i < E; i += stride) {
        atomicAdd(&dr[rowi[i]], 1);
        atomicAdd(&dc[coli[i]], 1);
    }
}

__global__ void pseudo_kernel(const int* __restrict__ rowi, const int* __restrict__ coli,
                              const int* __restrict__ dr, const int* __restrict__ dc,
                              float2* __restrict__ pseudo, int E) {
    int i = blockIdx.x * blockDim.x + threadIdx.x;
    int stride = gridDim.x * blockDim.x;
    for (; i < E; i += stride) {
        float a = rsqrtf((float)dr[rowi[i]] + 1.0f);
        float b = rsqrtf((float)dc[coli[i]] + 1.0f);
        pseudo[i] = make_float2(a, b);
    }
}

// ---------------- per-edge gauss coefficients (K=3) ----------------
// ps = tanh(pseudo @ ppw + ppb); g_k = exp(-0.5 * sum_d ((ps_d - mu[k,d]) * isg[k,d])^2)
__global__ void gauss_kernel(const float2* __restrict__ pseudo,
                             const float* __restrict__ ppw,  // [2,2] row-major
                             const float* __restrict__ ppb,  // [2]
                             const float* __restrict__ mu,   // [3,2]
                             const float* __restrict__ isg,  // [3,2]
                             float4* __restrict__ gauss, int E) {
    int i = blockIdx.x * blockDim.x + threadIdx.x;
    int stride = gridDim.x * blockDim.x;
    float w00 = ppw[0], w01 = ppw[1], w10 = ppw[2], w11 = ppw[3];
    float b0 = ppb[0], b1 = ppb[1];
    float m00 = mu[0], m01 = mu[1], m10 = mu[2], m11 = mu[3], m20 = mu[4], m21 = mu[5];
    float s00 = isg[0], s01 = isg[1], s10 = isg[2], s11 = isg[3], s20 = isg[4], s21 = isg[5];
    for (; i < E; i += stride) {
        float2 p = pseudo[i];
        float ps0 = tanhf(fmaf(p.y, w10, fmaf(p.x, w00, b0)));
        float ps1 = tanhf(fmaf(p.y, w11, fmaf(p.x, w01, b1)));
        float d0, d1;
        d0 = (ps0 - m00) * s00; d1 = (ps1 - m01) * s01;
        float g0 = expf(-0.5f * (d0 * d0 + d1 * d1));
        d0 = (ps0 - m10) * s10; d1 = (ps1 - m11) * s11;
        float g1 = expf(-0.5f * (d0 * d0 + d1 * d1));
        d0 = (ps0 - m20) * s20; d1 = (ps1 - m21) * s21;
        float g2 = expf(-0.5f * (d0 * d0 + d1 * d1));
        gauss[i] = make_float4(g0, g1, g2, 0.0f);
    }
}

// ---------------- GEMM: Y[M,NC] = X[M,KDIM] @ W[KDIM,NC] + b ----------------
// Weights + X-tile staged in LDS. blockDim=256, ROWS rows per block.
template <int KDIM, int NC, int ROWS>
__global__ __launch_bounds__(256) void gemm_bias(const float* __restrict__ X,
                                                 const float* __restrict__ W,
                                                 const float* __restrict__ Bv,
                                                 float* __restrict__ Y, int M) {
    constexpr int TPR = 256 / ROWS;  // threads per row
    constexpr int CPT = NC / TPR;    // cols per thread (contiguous)
    __shared__ __align__(16) float Ws[KDIM * NC];
    __shared__ float Bs[NC];
    __shared__ float Xs[ROWS][KDIM + 1];  // +1 pad: avoid bank conflicts on Xs[r][k]

    for (int i = threadIdx.x; i < KDIM * NC; i += 256) Ws[i] = W[i];
    if (threadIdx.x < NC) Bs[threadIdx.x] = Bv[threadIdx.x];
    int row0 = blockIdx.x * ROWS;
    for (int i = threadIdx.x; i < ROWS * KDIM; i += 256) {
        int r = i / KDIM, k = i % KDIM;
        int gr = row0 + r;
        Xs[r][k] = (gr < M) ? X[(size_t)gr * KDIM + k] : 0.0f;
    }
    __syncthreads();

    int r = threadIdx.x / TPR;
    int lc = threadIdx.x % TPR;
    int gr = row0 + r;
    if (gr >= M) return;

    float acc[CPT];
#pragma unroll
    for (int j = 0; j < CPT; ++j) acc[j] = Bs[lc * CPT + j];
    for (int k = 0; k < KDIM; ++k) {
        float xv = Xs[r][k];
        const float* wr = &Ws[k * NC + lc * CPT];
#pragma unroll
        for (int j = 0; j < CPT; ++j) acc[j] = fmaf(xv, wr[j], acc[j]);
    }
    float* yr = Y + (size_t)gr * NC + lc * CPT;
#pragma unroll
    for (int j = 0; j < CPT; ++j) yr[j] = acc[j];
}

// ---------------- edge message + scatter-add (float4 vectorized) ----------------
// L = C/4 lanes per edge; lane c owns channels [4c,4c+4). hp is float4 rows of 3*L.
// msg = sum_k g_k * hp4[row, k*L + c]
template <int C>
__global__ __launch_bounds__(256) void edge_kernel(const int* __restrict__ rowi,
                                                   const int* __restrict__ coli,
                                                   const float4* __restrict__ gauss,
                                                   const float4* __restrict__ hp,
                                                   float* __restrict__ agg, int E) {
    constexpr int L = C / 4;
    int t = blockIdx.x * blockDim.x + threadIdx.x;
    int c = t & (L - 1);
    long e = t / L;
    long stride = (long)gridDim.x * blockDim.x / L;
    for (; e < E; e += stride) {
        int r = rowi[e];
        int d = coli[e];
        float4 g = gauss[e];
        const float4* hr = hp + (size_t)r * (3 * L) + c;
        float4 a = hr[0], b = hr[L], q = hr[2 * L];
        float vx = g.x * a.x + g.y * b.x + g.z * q.x;
        float vy = g.x * a.y + g.y * b.y + g.z * q.y;
        float vz = g.x * a.z + g.y * b.z + g.z * q.z;
        float vw = g.x * a.w + g.y * b.w + g.z * q.w;
        float* ap = agg + (size_t)d * C + 4 * c;
        atomicAdd(ap + 0, vx);
        atomicAdd(ap + 1, vy);
        atomicAdd(ap + 2, vz);
        atomicAdd(ap + 3, vw);
    }
}

// ---------------- BN stats: per-channel sum & sumsq ----------------
template <int C>
__global__ __launch_bounds__(256) void bn_stats(const float* __restrict__ x, int Nn,
                                                float* __restrict__ sums) {
    constexpr int G = 256 / C;
    int c = threadIdx.x % C;
    int g = threadIdx.x / C;
    float s = 0.0f, ss = 0.0f;
    int totalG = gridDim.x * G;
    for (int r = blockIdx.x * G + g; r < Nn; r += totalG) {
        float v = x[(size_t)r * C + c];
        s += v;
        ss += v * v;
    }
    __shared__ float ls[256], lss[256];
    ls[threadIdx.x] = s;
    lss[threadIdx.x] = ss;
    __syncthreads();
    if (threadIdx.x < C) {
        float ts = 0.0f, tss = 0.0f;
#pragma unroll
        for (int gg = 0; gg < G; ++gg) {
            ts += ls[gg * C + threadIdx.x];
            tss += lss[gg * C + threadIdx.x];
        }
        atomicAdd(&sums[threadIdx.x], ts);
        atomicAdd(&sums[C + threadIdx.x], tss);
    }
}

// ---------------- BN apply + relu (+ residual) ----------------
template <int C, bool RES>
__global__ __launch_bounds__(256) void bn_apply(const float* __restrict__ agg,
                                                const float* __restrict__ sums,
                                                const float* __restrict__ gam,
                                                const float* __restrict__ bet,
                                                const float* __restrict__ hin,
                                                float* __restrict__ hout, int Nn) {
    size_t i = (size_t)blockIdx.x * blockDim.x + threadIdx.x;
    size_t tot = (size_t)Nn * C;
    size_t stride = (size_t)gridDim.x * blockDim.x;
    float invN = 1.0f / (float)Nn;
    for (; i < tot; i += stride) {
        int c = (int)(i & (C - 1));
        float mean = sums[c] * invN;
        float var = sums[C + c] * invN - mean * mean;
        float scale = gam[c] * rsqrtf(var + EPS);
        float v = (agg[i] - mean) * scale + bet[c];
        v = fmaxf(v, 0.0f);
        if (RES) v += hin[i];
        hout[i] = v;
    }
}

extern "C" void kernel_launch(void* const* d_in, const int* in_sizes, int n_in,
                              void* d_out, int out_size, void* d_ws, size_t ws_size,
                              hipStream_t stream) {
    const float* feature = (const float*)d_in[0];
    const float* emb_w = (const float*)d_in[1];
    const float* emb_b = (const float*)d_in[2];
    const float* fc_w = (const float*)d_in[3];    // [3,64,192]
    const float* fc_b = (const float*)d_in[4];    // [3,192]
    const float* mu = (const float*)d_in[5];      // [3,3,2]
    const float* isg = (const float*)d_in[6];     // [3,3,2]
    const float* pp_w = (const float*)d_in[7];    // [3,2,2]
    const float* pp_b = (const float*)d_in[8];    // [3,2]
    const float* bn_g = (const float*)d_in[9];    // [3,64]
    const float* bn_b = (const float*)d_in[10];   // [3,64]
    const float* fc_w_l = (const float*)d_in[11]; // [64,48]
    const float* fc_b_l = (const float*)d_in[12]; // [48]
    const float* mu_l = (const float*)d_in[13];   // [3,2]
    const float* isg_l = (const float*)d_in[14];  // [3,2]
    const float* pp_w_l = (const float*)d_in[15]; // [2,2]
    const float* pp_b_l = (const float*)d_in[16]; // [2]
    const float* bn_g_l = (const float*)d_in[17]; // [16]
    const float* bn_b_l = (const float*)d_in[18]; // [16]
    const int* edge = (const int*)d_in[19];       // [2,E] int32

    const int N = in_sizes[0] / 128;
    const int E = in_sizes[19] / 2;
    const int* rowi = edge;
    const int* coli = edge + E;

    char* ws = (char*)d_ws;
    size_t off = 0;
    auto alloc = [&](size_t sz) -> void* {
        void* p = ws + off;
        off += (sz + 255) & ~(size_t)255;
        return p;
    };
    int* dr = (int*)alloc((size_t)N * 4);
    int* dc = (int*)alloc((size_t)N * 4);
    float2* pseudo = (float2*)alloc((size_t)E * 8);
    float4* gauss = (float4*)alloc((size_t)E * 16);
    float* h = (float*)alloc((size_t)N * 64 * 4);
    float* hp = (float*)alloc((size_t)N * 192 * 4);
    float* agg = (float*)alloc((size_t)N * 64 * 4);
    float* sums = (float*)alloc(2 * 64 * 4);
    (void)ws_size; // total ~84 MB

    hipMemsetAsync(dr, 0, (size_t)N * 4, stream);
    hipMemsetAsync(dc, 0, (size_t)N * 4, stream);
    degree_kernel<<<2048, 256, 0, stream>>>(rowi, coli, dr, dc, E);
    pseudo_kernel<<<2048, 256, 0, stream>>>(rowi, coli, dr, dc, pseudo, E);

    // h = feature @ emb_w + emb_b   [N,128]x[128,64]
    gemm_bias<128, 64, 32><<<(N + 31) / 32, 256, 0, stream>>>(feature, emb_w, emb_b, h, N);

    for (int i = 0; i < 3; ++i) {
        gauss_kernel<<<1024, 256, 0, stream>>>(pseudo, pp_w + i * 4, pp_b + i * 2,
                                               mu + i * 6, isg + i * 6, gauss, E);
        // hp = h @ fc_w[i] + fc_b[i]   [N,64]x[64,192]
        gemm_bias<64, 192, 32><<<(N + 31) / 32, 256, 0, stream>>>(
            h, fc_w + (size_t)i * 64 * 192, fc_b + (size_t)i * 192, hp, N);
        hipMemsetAsync(agg, 0, (size_t)N * 64 * 4, stream);
        edge_kernel<64><<<8192, 256, 0, stream>>>(rowi, coli, gauss, (const float4*)hp, agg, E);
        hipMemsetAsync(sums, 0, 2 * 64 * 4, stream);
        bn_stats<64><<<256, 256, 0, stream>>>(agg, N, sums);
        bn_apply<64, true><<<2048, 256, 0, stream>>>(agg, sums, bn_g + i * 64, bn_b + i * 64,
                                                     h, h, N);
    }

    // last layer: out = 16 classes, no residual, write d_out (f32)
    gauss_kernel<<<1024, 256, 0, stream>>>(pseudo, pp_w_l, pp_b_l, mu_l, isg_l, gauss, E);
    gemm_bias<64, 48, 32><<<(N + 31) / 32, 256, 0, stream>>>(h, fc_w_l, fc_b_l, hp, N);
    hipMemsetAsync(agg, 0, (size_t)N * 16 * 4, stream);
    edge_kernel<16><<<8192, 256, 0, stream>>>(rowi, coli, gauss, (const float4*)hp, agg, E);
    hipMemsetAsync(sums, 0, 2 * 16 * 4, stream);
    bn_stats<16><<<256, 256, 0, stream>>>(agg, N, sums);
    bn_apply<16, false><<<2048, 256, 0, stream>>>(agg, sums, bn_g_l, bn_b_l, nullptr,
                                                  (float*)d_out, N);
}

// Round 5
// 886.296 us; speedup vs baseline: 3.0817x; 3.0817x over previous
//
#include <hip/hip_runtime.h>
#include <cstdint>
#include <cstddef>

// MoNet (GMM graph conv) forward, MI355X — round 5 (= round-4 resubmit; CSR pull unbenched).
// CSR pull aggregation (no atomics) + algebraic reorder: aggregate h (256B/edge)
// into m[N,3*64(+G)] then GEMM with rearranged fc_w. fp32 (no fp32 MFMA on CDNA4).

#define EPS 1e-5f
#define KAUG 196  // 192 m-columns + 3 gauss-sum columns + 1 zero pad

// ---------------- degree ----------------
__global__ void degree_kernel(const int* __restrict__ rowi, const int* __restrict__ coli,
                              int* __restrict__ dr, int* __restrict__ dc, int E) {
    int i = blockIdx.x * blockDim.x + threadIdx.x;
    int stride = gridDim.x * blockDim.x;
    for (; i < E; i += stride) {
        atomicAdd(&dr[rowi[i]], 1);
        atomicAdd(&dc[coli[i]], 1);
    }
}

__global__ void pseudo_kernel(const int* __restrict__ rowi, const int* __restrict__ coli,
                              const int* __restrict__ dr, const int* __restrict__ dc,
                              float2* __restrict__ pseudo, int E) {
    int i = blockIdx.x * blockDim.x + threadIdx.x;
    int stride = gridDim.x * blockDim.x;
    for (; i < E; i += stride) {
        float a = rsqrtf((float)dr[rowi[i]] + 1.0f);
        float b = rsqrtf((float)dc[coli[i]] + 1.0f);
        pseudo[i] = make_float2(a, b);
    }
}

// ---------------- exclusive scan of in-degree -> start & cursor ----------------
__global__ __launch_bounds__(1024) void scan_kernel(const int* __restrict__ cnt,
                                                    int* __restrict__ start,
                                                    int* __restrict__ cursor, int Nn) {
    const int T = 1024;
    int t = threadIdx.x;
    int per = (Nn + T - 1) / T;
    int lo = t * per;
    int hi = lo + per; if (hi > Nn) hi = Nn;
    int s = 0;
    for (int i = lo; i < hi; ++i) s += cnt[i];
    __shared__ int sm[T];
    sm[t] = s;
    __syncthreads();
    for (int d = 1; d < T; d <<= 1) {
        int v = (t >= d) ? sm[t - d] : 0;
        __syncthreads();
        sm[t] += v;
        __syncthreads();
    }
    int base = (t == 0) ? 0 : sm[t - 1];
    for (int i = lo; i < hi; ++i) {
        start[i] = base;
        cursor[i] = base;
        base += cnt[i];
    }
}

// ---------------- counting-sort scatter: group edges by dst ----------------
__global__ void csr_scatter(const int* __restrict__ rowi, const int* __restrict__ coli,
                            const float2* __restrict__ pseudo, int* __restrict__ cursor,
                            int* __restrict__ rowPerm, float2* __restrict__ pseudoPerm, int E) {
    int i = blockIdx.x * blockDim.x + threadIdx.x;
    int stride = gridDim.x * blockDim.x;
    for (; i < E; i += stride) {
        int d = coli[i];
        int pos = atomicAdd(&cursor[d], 1);
        rowPerm[pos] = rowi[i];
        pseudoPerm[pos] = pseudo[i];
    }
}

// ---------------- per-edge gauss coefficients (K=3), permuted order ----------------
__global__ void gauss_kernel(const float2* __restrict__ pseudo,
                             const float* __restrict__ ppw,  // [2,2] row-major
                             const float* __restrict__ ppb,  // [2]
                             const float* __restrict__ mu,   // [3,2]
                             const float* __restrict__ isg,  // [3,2]
                             float4* __restrict__ gauss, int E) {
    int i = blockIdx.x * blockDim.x + threadIdx.x;
    int stride = gridDim.x * blockDim.x;
    float w00 = ppw[0], w01 = ppw[1], w10 = ppw[2], w11 = ppw[3];
    float b0 = ppb[0], b1 = ppb[1];
    float m00 = mu[0], m01 = mu[1], m10 = mu[2], m11 = mu[3], m20 = mu[4], m21 = mu[5];
    float s00 = isg[0], s01 = isg[1], s10 = isg[2], s11 = isg[3], s20 = isg[4], s21 = isg[5];
    for (; i < E; i += stride) {
        float2 p = pseudo[i];
        float ps0 = tanhf(fmaf(p.y, w10, fmaf(p.x, w00, b0)));
        float ps1 = tanhf(fmaf(p.y, w11, fmaf(p.x, w01, b1)));
        float d0, d1;
        d0 = (ps0 - m00) * s00; d1 = (ps1 - m01) * s01;
        float g0 = expf(-0.5f * (d0 * d0 + d1 * d1));
        d0 = (ps0 - m10) * s10; d1 = (ps1 - m11) * s11;
        float g1 = expf(-0.5f * (d0 * d0 + d1 * d1));
        d0 = (ps0 - m20) * s20; d1 = (ps1 - m21) * s21;
        float g2 = expf(-0.5f * (d0 * d0 + d1 * d1));
        gauss[i] = make_float4(g0, g1, g2, 0.0f);
    }
}

// ---------------- W2 transform: W2[(k*64+j), c] = fc_w[j, k*C + c]; bias rows ----------------
// W2 is [KAUG, C]: rows 0..191 weights, 192..194 = fc_b[k*C+c], 195 = 0
__global__ void w2_transform(const float* __restrict__ fcw, const float* __restrict__ fcb,
                             float* __restrict__ W2, int C) {
    int i = blockIdx.x * blockDim.x + threadIdx.x;
    int tot = KAUG * C;
    if (i >= tot) return;
    int r = i / C, c = i - r * C;
    float v;
    if (r < 192) {
        int k = r >> 6, j = r & 63;
        v = fcw[j * (3 * C) + k * C + c];
    } else if (r < 195) {
        v = fcb[(r - 192) * C + c];
    } else {
        v = 0.0f;
    }
    W2[i] = v;
}

// ---------------- CSR pull: one wave per dst node, 4-deep MLP ----------------
// m[d, k*64+lane] = sum_{e in CSR[d]} g_k(e) * h[row(e), lane]; m[d,192+k]=sum g_k
__global__ __launch_bounds__(256) void pull_kernel(const int* __restrict__ start,
                                                   const int* __restrict__ cnt,
                                                   const int* __restrict__ rowPerm,
                                                   const float4* __restrict__ gauss,
                                                   const float* __restrict__ h,
                                                   float* __restrict__ m, int Nn) {
    int wave = threadIdx.x >> 6;
    int lane = threadIdx.x & 63;
    int d = blockIdx.x * 4 + wave;
    if (d >= Nn) return;
    int s = start[d];
    int e = s + cnt[d];
    float a0 = 0.0f, a1 = 0.0f, a2 = 0.0f;
    float s0 = 0.0f, s1 = 0.0f, s2 = 0.0f;
    const float* hl = h + lane;
    int i = s;
    for (; i + 3 < e; i += 4) {
        int r0 = rowPerm[i], r1 = rowPerm[i + 1], r2 = rowPerm[i + 2], r3 = rowPerm[i + 3];
        float4 g0 = gauss[i], g1 = gauss[i + 1], g2 = gauss[i + 2], g3 = gauss[i + 3];
        float h0 = hl[(size_t)r0 * 64], h1 = hl[(size_t)r1 * 64];
        float h2 = hl[(size_t)r2 * 64], h3 = hl[(size_t)r3 * 64];
        a0 = fmaf(g0.x, h0, a0); a1 = fmaf(g0.y, h0, a1); a2 = fmaf(g0.z, h0, a2);
        a0 = fmaf(g1.x, h1, a0); a1 = fmaf(g1.y, h1, a1); a2 = fmaf(g1.z, h1, a2);
        a0 = fmaf(g2.x, h2, a0); a1 = fmaf(g2.y, h2, a1); a2 = fmaf(g2.z, h2, a2);
        a0 = fmaf(g3.x, h3, a0); a1 = fmaf(g3.y, h3, a1); a2 = fmaf(g3.z, h3, a2);
        s0 += g0.x + g1.x + g2.x + g3.x;
        s1 += g0.y + g1.y + g2.y + g3.y;
        s2 += g0.z + g1.z + g2.z + g3.z;
    }
    for (; i < e; ++i) {
        int r0 = rowPerm[i];
        float4 g0 = gauss[i];
        float h0 = hl[(size_t)r0 * 64];
        a0 = fmaf(g0.x, h0, a0); a1 = fmaf(g0.y, h0, a1); a2 = fmaf(g0.z, h0, a2);
        s0 += g0.x; s1 += g0.y; s2 += g0.z;
    }
    float* mr = m + (size_t)d * KAUG;
    mr[lane] = a0;
    mr[64 + lane] = a1;
    mr[128 + lane] = a2;
    if (lane < 3) mr[192 + lane] = (lane == 0) ? s0 : ((lane == 1) ? s1 : s2);
    if (lane == 3) mr[195] = 0.0f;
}

// ---------------- GEMM: Y[M,NC] = X[M,KDIM] @ W[KDIM,NC] (+ b if Bv) ----------------
template <int KDIM, int NC, int ROWS>
__global__ __launch_bounds__(256) void gemm_bias(const float* __restrict__ X,
                                                 const float* __restrict__ W,
                                                 const float* __restrict__ Bv,
                                                 float* __restrict__ Y, int M) {
    constexpr int TPR = 256 / ROWS;  // threads per row
    constexpr int CPT = NC / TPR;    // cols per thread (contiguous)
    __shared__ __align__(16) float Ws[KDIM * NC];
    __shared__ float Bs[NC];
    __shared__ float Xs[ROWS][KDIM + 1];

    for (int i = threadIdx.x; i < KDIM * NC; i += 256) Ws[i] = W[i];
    if (Bv && threadIdx.x < NC) Bs[threadIdx.x] = Bv[threadIdx.x];
    int row0 = blockIdx.x * ROWS;
    for (int i = threadIdx.x; i < ROWS * KDIM; i += 256) {
        int r = i / KDIM, k = i - r * KDIM;
        int gr = row0 + r;
        Xs[r][k] = (gr < M) ? X[(size_t)gr * KDIM + k] : 0.0f;
    }
    __syncthreads();

    int r = threadIdx.x / TPR;
    int lc = threadIdx.x % TPR;
    int gr = row0 + r;
    if (gr >= M) return;

    float acc[CPT];
#pragma unroll
    for (int j = 0; j < CPT; ++j) acc[j] = Bv ? Bs[lc * CPT + j] : 0.0f;
    for (int k = 0; k < KDIM; ++k) {
        float xv = Xs[r][k];
        const float* wr = &Ws[k * NC + lc * CPT];
#pragma unroll
        for (int j = 0; j < CPT; ++j) acc[j] = fmaf(xv, wr[j], acc[j]);
    }
    float* yr = Y + (size_t)gr * NC + lc * CPT;
#pragma unroll
    for (int j = 0; j < CPT; ++j) yr[j] = acc[j];
}

// ---------------- BN stats: per-channel sum & sumsq ----------------
template <int C>
__global__ __launch_bounds__(256) void bn_stats(const float* __restrict__ x, int Nn,
                                                float* __restrict__ sums) {
    constexpr int G = 256 / C;
    int c = threadIdx.x % C;
    int g = threadIdx.x / C;
    float s = 0.0f, ss = 0.0f;
    int totalG = gridDim.x * G;
    for (int r = blockIdx.x * G + g; r < Nn; r += totalG) {
        float v = x[(size_t)r * C + c];
        s += v;
        ss += v * v;
    }
    __shared__ float ls[256], lss[256];
    ls[threadIdx.x] = s;
    lss[threadIdx.x] = ss;
    __syncthreads();
    if (threadIdx.x < C) {
        float ts = 0.0f, tss = 0.0f;
#pragma unroll
        for (int gg = 0; gg < G; ++gg) {
            ts += ls[gg * C + threadIdx.x];
            tss += lss[gg * C + threadIdx.x];
        }
        atomicAdd(&sums[threadIdx.x], ts);
        atomicAdd(&sums[C + threadIdx.x], tss);
    }
}

// ---------------- BN apply + relu (+ residual) ----------------
template <int C, bool RES>
__global__ __launch_bounds__(256) void bn_apply(const float* __restrict__ agg,
                                                const float* __restrict__ sums,
                                                const float* __restrict__ gam,
                                                const float* __restrict__ bet,
                                                const float* __restrict__ hin,
                                                float* __restrict__ hout, int Nn) {
    size_t i = (size_t)blockIdx.x * blockDim.x + threadIdx.x;
    size_t tot = (size_t)Nn * C;
    size_t stride = (size_t)gridDim.x * blockDim.x;
    float invN = 1.0f / (float)Nn;
    for (; i < tot; i += stride) {
        int c = (int)(i & (C - 1));
        float mean = sums[c] * invN;
        float var = sums[C + c] * invN - mean * mean;
        float scale = gam[c] * rsqrtf(var + EPS);
        float v = (agg[i] - mean) * scale + bet[c];
        v = fmaxf(v, 0.0f);
        if (RES) v += hin[i];
        hout[i] = v;
    }
}

extern "C" void kernel_launch(void* const* d_in, const int* in_sizes, int n_in,
                              void* d_out, int out_size, void* d_ws, size_t ws_size,
                              hipStream_t stream) {
    const float* feature = (const float*)d_in[0];
    const float* emb_w = (const float*)d_in[1];
    const float* emb_b = (const float*)d_in[2];
    const float* fc_w = (const float*)d_in[3];    // [3,64,192]
    const float* fc_b = (const float*)d_in[4];    // [3,192]
    const float* mu = (const float*)d_in[5];      // [3,3,2]
    const float* isg = (const float*)d_in[6];     // [3,3,2]
    const float* pp_w = (const float*)d_in[7];    // [3,2,2]
    const float* pp_b = (const float*)d_in[8];    // [3,2]
    const float* bn_g = (const float*)d_in[9];    // [3,64]
    const float* bn_b = (const float*)d_in[10];   // [3,64]
    const float* fc_w_l = (const float*)d_in[11]; // [64,48]
    const float* fc_b_l = (const float*)d_in[12]; // [48]
    const float* mu_l = (const float*)d_in[13];   // [3,2]
    const float* isg_l = (const float*)d_in[14];  // [3,2]
    const float* pp_w_l = (const float*)d_in[15]; // [2,2]
    const float* pp_b_l = (const float*)d_in[16]; // [2]
    const float* bn_g_l = (const float*)d_in[17]; // [16]
    const float* bn_b_l = (const float*)d_in[18]; // [16]
    const int* edge = (const int*)d_in[19];       // [2,E] int32

    const int N = in_sizes[0] / 128;
    const int E = in_sizes[19] / 2;
    const int* rowi = edge;
    const int* coli = edge + E;

    char* ws = (char*)d_ws;
    size_t off = 0;
    auto alloc = [&](size_t sz) -> void* {
        void* p = ws + off;
        off += (sz + 255) & ~(size_t)255;
        return p;
    };
    int* dr = (int*)alloc((size_t)N * 4);
    int* dc = (int*)alloc((size_t)N * 4);           // in-degree by col (CSR counts)
    int* startv = (int*)alloc((size_t)N * 4);
    int* cursor = (int*)alloc((size_t)N * 4);
    float2* pseudo = (float2*)alloc((size_t)E * 8);
    float2* pseudoPerm = (float2*)alloc((size_t)E * 8);
    int* rowPerm = (int*)alloc((size_t)E * 4);
    float4* gauss = (float4*)alloc((size_t)E * 16);
    float* h = (float*)alloc((size_t)N * 64 * 4);
    float* m = (float*)alloc((size_t)N * KAUG * 4);
    float* agg = (float*)alloc((size_t)N * 64 * 4);
    float* W2 = (float*)alloc((size_t)KAUG * 64 * 4);
    float* sums = (float*)alloc(2 * 64 * 4);
    (void)ws_size; // ~95 MB

    hipMemsetAsync(dr, 0, (size_t)N * 4, stream);
    hipMemsetAsync(dc, 0, (size_t)N * 4, stream);
    degree_kernel<<<2048, 256, 0, stream>>>(rowi, coli, dr, dc, E);
    pseudo_kernel<<<2048, 256, 0, stream>>>(rowi, coli, dr, dc, pseudo, E);
    scan_kernel<<<1, 1024, 0, stream>>>(dc, startv, cursor, N);
    csr_scatter<<<2048, 256, 0, stream>>>(rowi, coli, pseudo, cursor, rowPerm, pseudoPerm, E);

    // h = feature @ emb_w + emb_b   [N,128]x[128,64]
    gemm_bias<128, 64, 32><<<(N + 31) / 32, 256, 0, stream>>>(feature, emb_w, emb_b, h, N);

    const int pullBlocks = (N + 3) / 4;
    for (int i = 0; i < 3; ++i) {
        gauss_kernel<<<1024, 256, 0, stream>>>(pseudoPerm, pp_w + i * 4, pp_b + i * 2,
                                               mu + i * 6, isg + i * 6, gauss, E);
        w2_transform<<<(KAUG * 64 + 255) / 256, 256, 0, stream>>>(
            fc_w + (size_t)i * 64 * 192, fc_b + (size_t)i * 192, W2, 64);
        pull_kernel<<<pullBlocks, 256, 0, stream>>>(startv, dc, rowPerm, gauss, h, m, N);
        gemm_bias<KAUG, 64, 16><<<(N + 15) / 16, 256, 0, stream>>>(m, W2, nullptr, agg, N);
        hipMemsetAsync(sums, 0, 2 * 64 * 4, stream);
        bn_stats<64><<<256, 256, 0, stream>>>(agg, N, sums);
        bn_apply<64, true><<<2048, 256, 0, stream>>>(agg, sums, bn_g + i * 64, bn_b + i * 64,
                                                     h, h, N);
    }

    // last layer: 16 classes, no residual, write d_out (f32)
    gauss_kernel<<<1024, 256, 0, stream>>>(pseudoPerm, pp_w_l, pp_b_l, mu_l, isg_l, gauss, E);
    w2_transform<<<(KAUG * 16 + 255) / 256, 256, 0, stream>>>(fc_w_l, fc_b_l, W2, 16);
    pull_kernel<<<pullBlocks, 256, 0, stream>>>(startv, dc, rowPerm, gauss, h, m, N);
    gemm_bias<KAUG, 16, 32><<<(N + 31) / 32, 256, 0, stream>>>(m, W2, nullptr, agg, N);
    hipMemsetAsync(sums, 0, 2 * 16 * 4, stream);
    bn_stats<16><<<256, 256, 0, stream>>>(agg, N, sums);
    bn_apply<16, false><<<2048, 256, 0, stream>>>(agg, sums, bn_g_l, bn_b_l, nullptr,
                                                  (float*)d_out, N);
}

// Round 9
// 785.715 us; speedup vs baseline: 3.4762x; 1.1280x over previous
//
#include <hip/hip_runtime.h>
#include <cstdint>
#include <cstddef>

// MoNet (GMM graph conv) forward, MI355X — round 9 (= round-8 resubmit; scan fix +
// memset removal still unbenched due to GPU acquisition timeouts).
// CSR pull aggregation (no atomics) + algebraic reorder (round 5, 886 us) with the
// single-block scan (110 us, 0.14% occupancy) replaced by a 3-phase hierarchical scan.

#define EPS 1e-5f
#define KAUG 196  // 192 m-columns + 3 gauss-sum columns + 1 zero pad

// ---------------- degree ----------------
__global__ void degree_kernel(const int* __restrict__ rowi, const int* __restrict__ coli,
                              int* __restrict__ dr, int* __restrict__ dc, int E) {
    int i = blockIdx.x * blockDim.x + threadIdx.x;
    int stride = gridDim.x * blockDim.x;
    for (; i < E; i += stride) {
        atomicAdd(&dr[rowi[i]], 1);
        atomicAdd(&dc[coli[i]], 1);
    }
}

__global__ void pseudo_kernel(const int* __restrict__ rowi, const int* __restrict__ coli,
                              const int* __restrict__ dr, const int* __restrict__ dc,
                              float2* __restrict__ pseudo, int E) {
    int i = blockIdx.x * blockDim.x + threadIdx.x;
    int stride = gridDim.x * blockDim.x;
    for (; i < E; i += stride) {
        float a = rsqrtf((float)dr[rowi[i]] + 1.0f);
        float b = rsqrtf((float)dc[coli[i]] + 1.0f);
        pseudo[i] = make_float2(a, b);
    }
}

// ---------------- hierarchical exclusive scan (3 phases) ----------------
__global__ __launch_bounds__(256) void scan_phase1(const int* __restrict__ cnt,
                                                   int* __restrict__ partial,
                                                   int* __restrict__ blockSum, int Nn) {
    __shared__ int sm[256];
    int tid = blockIdx.x * 256 + threadIdx.x;
    int v = (tid < Nn) ? cnt[tid] : 0;
    sm[threadIdx.x] = v;
    __syncthreads();
    for (int d = 1; d < 256; d <<= 1) {
        int t = (threadIdx.x >= d) ? sm[threadIdx.x - d] : 0;
        __syncthreads();
        sm[threadIdx.x] += t;
        __syncthreads();
    }
    if (tid < Nn) partial[tid] = sm[threadIdx.x] - v;  // exclusive within block
    if (threadIdx.x == 255) blockSum[blockIdx.x] = sm[255];
}

__global__ __launch_bounds__(1024) void scan_phase2(const int* __restrict__ blockSum,
                                                    int* __restrict__ blockOff, int B) {
    __shared__ int sm[1024];
    int v = (threadIdx.x < B) ? blockSum[threadIdx.x] : 0;
    sm[threadIdx.x] = v;
    __syncthreads();
    for (int d = 1; d < 1024; d <<= 1) {
        int t = (threadIdx.x >= d) ? sm[threadIdx.x - d] : 0;
        __syncthreads();
        sm[threadIdx.x] += t;
        __syncthreads();
    }
    if (threadIdx.x < B) blockOff[threadIdx.x] = sm[threadIdx.x] - v;  // exclusive
}

__global__ __launch_bounds__(256) void scan_phase3(const int* __restrict__ partial,
                                                   const int* __restrict__ blockOff,
                                                   int* __restrict__ start,
                                                   int* __restrict__ cursor, int Nn) {
    int tid = blockIdx.x * 256 + threadIdx.x;
    if (tid < Nn) {
        int s = partial[tid] + blockOff[blockIdx.x];
        start[tid] = s;
        cursor[tid] = s;
    }
}

// ---------------- counting-sort scatter: group edges by dst ----------------
__global__ void csr_scatter(const int* __restrict__ rowi, const int* __restrict__ coli,
                            const float2* __restrict__ pseudo, int* __restrict__ cursor,
                            int* __restrict__ rowPerm, float2* __restrict__ pseudoPerm, int E) {
    int i = blockIdx.x * blockDim.x + threadIdx.x;
    int stride = gridDim.x * blockDim.x;
    for (; i < E; i += stride) {
        int d = coli[i];
        int pos = atomicAdd(&cursor[d], 1);
        rowPerm[pos] = rowi[i];
        pseudoPerm[pos] = pseudo[i];
    }
}

// ---------------- per-edge gauss coefficients (K=3), permuted order ----------------
__global__ void gauss_kernel(const float2* __restrict__ pseudo,
                             const float* __restrict__ ppw,  // [2,2] row-major
                             const float* __restrict__ ppb,  // [2]
                             const float* __restrict__ mu,   // [3,2]
                             const float* __restrict__ isg,  // [3,2]
                             float4* __restrict__ gauss, int E) {
    int i = blockIdx.x * blockDim.x + threadIdx.x;
    int stride = gridDim.x * blockDim.x;
    float w00 = ppw[0], w01 = ppw[1], w10 = ppw[2], w11 = ppw[3];
    float b0 = ppb[0], b1 = ppb[1];
    float m00 = mu[0], m01 = mu[1], m10 = mu[2], m11 = mu[3], m20 = mu[4], m21 = mu[5];
    float s00 = isg[0], s01 = isg[1], s10 = isg[2], s11 = isg[3], s20 = isg[4], s21 = isg[5];
    for (; i < E; i += stride) {
        float2 p = pseudo[i];
        float ps0 = tanhf(fmaf(p.y, w10, fmaf(p.x, w00, b0)));
        float ps1 = tanhf(fmaf(p.y, w11, fmaf(p.x, w01, b1)));
        float d0, d1;
        d0 = (ps0 - m00) * s00; d1 = (ps1 - m01) * s01;
        float g0 = expf(-0.5f * (d0 * d0 + d1 * d1));
        d0 = (ps0 - m10) * s10; d1 = (ps1 - m11) * s11;
        float g1 = expf(-0.5f * (d0 * d0 + d1 * d1));
        d0 = (ps0 - m20) * s20; d1 = (ps1 - m21) * s21;
        float g2 = expf(-0.5f * (d0 * d0 + d1 * d1));
        gauss[i] = make_float4(g0, g1, g2, 0.0f);
    }
}

// ---------------- W2 transform: W2[(k*64+j), c] = fc_w[j, k*C + c]; bias rows ----------------
// W2 is [KAUG, C]: rows 0..191 weights, 192..194 = fc_b[k*C+c], 195 = 0
__global__ void w2_transform(const float* __restrict__ fcw, const float* __restrict__ fcb,
                             float* __restrict__ W2, int C) {
    int i = blockIdx.x * blockDim.x + threadIdx.x;
    int tot = KAUG * C;
    if (i >= tot) return;
    int r = i / C, c = i - r * C;
    float v;
    if (r < 192) {
        int k = r >> 6, j = r & 63;
        v = fcw[j * (3 * C) + k * C + c];
    } else if (r < 195) {
        v = fcb[(r - 192) * C + c];
    } else {
        v = 0.0f;
    }
    W2[i] = v;
}

// ---------------- CSR pull: one wave per dst node, 4-deep MLP ----------------
// m[d, k*64+lane] = sum_{e in CSR[d]} g_k(e) * h[row(e), lane]; m[d,192+k]=sum g_k
__global__ __launch_bounds__(256) void pull_kernel(const int* __restrict__ start,
                                                   const int* __restrict__ cnt,
                                                   const int* __restrict__ rowPerm,
                                                   const float4* __restrict__ gauss,
                                                   const float* __restrict__ h,
                                                   float* __restrict__ m, int Nn) {
    int wave = threadIdx.x >> 6;
    int lane = threadIdx.x & 63;
    int d = blockIdx.x * 4 + wave;
    if (d >= Nn) return;
    int s = start[d];
    int e = s + cnt[d];
    float a0 = 0.0f, a1 = 0.0f, a2 = 0.0f;
    float s0 = 0.0f, s1 = 0.0f, s2 = 0.0f;
    const float* hl = h + lane;
    int i = s;
    for (; i + 3 < e; i += 4) {
        int r0 = rowPerm[i], r1 = rowPerm[i + 1], r2 = rowPerm[i + 2], r3 = rowPerm[i + 3];
        float4 g0 = gauss[i], g1 = gauss[i + 1], g2 = gauss[i + 2], g3 = gauss[i + 3];
        float h0 = hl[(size_t)r0 * 64], h1 = hl[(size_t)r1 * 64];
        float h2 = hl[(size_t)r2 * 64], h3 = hl[(size_t)r3 * 64];
        a0 = fmaf(g0.x, h0, a0); a1 = fmaf(g0.y, h0, a1); a2 = fmaf(g0.z, h0, a2);
        a0 = fmaf(g1.x, h1, a0); a1 = fmaf(g1.y, h1, a1); a2 = fmaf(g1.z, h1, a2);
        a0 = fmaf(g2.x, h2, a0); a1 = fmaf(g2.y, h2, a1); a2 = fmaf(g2.z, h2, a2);
        a0 = fmaf(g3.x, h3, a0); a1 = fmaf(g3.y, h3, a1); a2 = fmaf(g3.z, h3, a2);
        s0 += g0.x + g1.x + g2.x + g3.x;
        s1 += g0.y + g1.y + g2.y + g3.y;
        s2 += g0.z + g1.z + g2.z + g3.z;
    }
    for (; i < e; ++i) {
        int r0 = rowPerm[i];
        float4 g0 = gauss[i];
        float h0 = hl[(size_t)r0 * 64];
        a0 = fmaf(g0.x, h0, a0); a1 = fmaf(g0.y, h0, a1); a2 = fmaf(g0.z, h0, a2);
        s0 += g0.x; s1 += g0.y; s2 += g0.z;
    }
    float* mr = m + (size_t)d * KAUG;
    mr[lane] = a0;
    mr[64 + lane] = a1;
    mr[128 + lane] = a2;
    if (lane < 3) mr[192 + lane] = (lane == 0) ? s0 : ((lane == 1) ? s1 : s2);
    if (lane == 3) mr[195] = 0.0f;
}

// ---------------- GEMM: Y[M,NC] = X[M,KDIM] @ W[KDIM,NC] (+ b if Bv) ----------------
template <int KDIM, int NC, int ROWS>
__global__ __launch_bounds__(256) void gemm_bias(const float* __restrict__ X,
                                                 const float* __restrict__ W,
                                                 const float* __restrict__ Bv,
                                                 float* __restrict__ Y, int M) {
    constexpr int TPR = 256 / ROWS;  // threads per row
    constexpr int CPT = NC / TPR;    // cols per thread (contiguous)
    __shared__ __align__(16) float Ws[KDIM * NC];
    __shared__ float Bs[NC];
    __shared__ float Xs[ROWS][KDIM + 1];

    for (int i = threadIdx.x; i < KDIM * NC; i += 256) Ws[i] = W[i];
    if (Bv && threadIdx.x < NC) Bs[threadIdx.x] = Bv[threadIdx.x];
    int row0 = blockIdx.x * ROWS;
    for (int i = threadIdx.x; i < ROWS * KDIM; i += 256) {
        int r = i / KDIM, k = i - r * KDIM;
        int gr = row0 + r;
        Xs[r][k] = (gr < M) ? X[(size_t)gr * KDIM + k] : 0.0f;
    }
    __syncthreads();

    int r = threadIdx.x / TPR;
    int lc = threadIdx.x % TPR;
    int gr = row0 + r;
    if (gr >= M) return;

    float acc[CPT];
#pragma unroll
    for (int j = 0; j < CPT; ++j) acc[j] = Bv ? Bs[lc * CPT + j] : 0.0f;
    for (int k = 0; k < KDIM; ++k) {
        float xv = Xs[r][k];
        const float* wr = &Ws[k * NC + lc * CPT];
#pragma unroll
        for (int j = 0; j < CPT; ++j) acc[j] = fmaf(xv, wr[j], acc[j]);
    }
    float* yr = Y + (size_t)gr * NC + lc * CPT;
#pragma unroll
    for (int j = 0; j < CPT; ++j) yr[j] = acc[j];
}

// ---------------- BN stats: per-channel sum & sumsq ----------------
template <int C>
__global__ __launch_bounds__(256) void bn_stats(const float* __restrict__ x, int Nn,
                                                float* __restrict__ sums) {
    constexpr int G = 256 / C;
    int c = threadIdx.x % C;
    int g = threadIdx.x / C;
    float s = 0.0f, ss = 0.0f;
    int totalG = gridDim.x * G;
    for (int r = blockIdx.x * G + g; r < Nn; r += totalG) {
        float v = x[(size_t)r * C + c];
        s += v;
        ss += v * v;
    }
    __shared__ float ls[256], lss[256];
    ls[threadIdx.x] = s;
    lss[threadIdx.x] = ss;
    __syncthreads();
    if (threadIdx.x < C) {
        float ts = 0.0f, tss = 0.0f;
#pragma unroll
        for (int gg = 0; gg < G; ++gg) {
            ts += ls[gg * C + threadIdx.x];
            tss += lss[gg * C + threadIdx.x];
        }
        atomicAdd(&sums[threadIdx.x], ts);
        atomicAdd(&sums[C + threadIdx.x], tss);
    }
}

// ---------------- BN apply + relu (+ residual) ----------------
template <int C, bool RES>
__global__ __launch_bounds__(256) void bn_apply(const float* __restrict__ agg,
                                                const float* __restrict__ sums,
                                                const float* __restrict__ gam,
                                                const float* __restrict__ bet,
                                                const float* __restrict__ hin,
                                                float* __restrict__ hout, int Nn) {
    size_t i = (size_t)blockIdx.x * blockDim.x + threadIdx.x;
    size_t tot = (size_t)Nn * C;
    size_t stride = (size_t)gridDim.x * blockDim.x;
    float invN = 1.0f / (float)Nn;
    for (; i < tot; i += stride) {
        int c = (int)(i & (C - 1));
        float mean = sums[c] * invN;
        float var = sums[C + c] * invN - mean * mean;
        float scale = gam[c] * rsqrtf(var + EPS);
        float v = (agg[i] - mean) * scale + bet[c];
        v = fmaxf(v, 0.0f);
        if (RES) v += hin[i];
        hout[i] = v;
    }
}

extern "C" void kernel_launch(void* const* d_in, const int* in_sizes, int n_in,
                              void* d_out, int out_size, void* d_ws, size_t ws_size,
                              hipStream_t stream) {
    const float* feature = (const float*)d_in[0];
    const float* emb_w = (const float*)d_in[1];
    const float* emb_b = (const float*)d_in[2];
    const float* fc_w = (const float*)d_in[3];    // [3,64,192]
    const float* fc_b = (const float*)d_in[4];    // [3,192]
    const float* mu = (const float*)d_in[5];      // [3,3,2]
    const float* isg = (const float*)d_in[6];     // [3,3,2]
    const float* pp_w = (const float*)d_in[7];    // [3,2,2]
    const float* pp_b = (const float*)d_in[8];    // [3,2]
    const float* bn_g = (const float*)d_in[9];    // [3,64]
    const float* bn_b = (const float*)d_in[10];   // [3,64]
    const float* fc_w_l = (const float*)d_in[11]; // [64,48]
    const float* fc_b_l = (const float*)d_in[12]; // [48]
    const float* mu_l = (const float*)d_in[13];   // [3,2]
    const float* isg_l = (const float*)d_in[14];  // [3,2]
    const float* pp_w_l = (const float*)d_in[15]; // [2,2]
    const float* pp_b_l = (const float*)d_in[16]; // [2]
    const float* bn_g_l = (const float*)d_in[17]; // [16]
    const float* bn_b_l = (const float*)d_in[18]; // [16]
    const int* edge = (const int*)d_in[19];       // [2,E] int32

    const int N = in_sizes[0] / 128;
    const int E = in_sizes[19] / 2;
    const int* rowi = edge;
    const int* coli = edge + E;

    char* ws = (char*)d_ws;
    size_t off = 0;
    auto alloc = [&](size_t sz) -> void* {
        void* p = ws + off;
        off += (sz + 255) & ~(size_t)255;
        return p;
    };
    int* dr = (int*)alloc((size_t)N * 4);
    int* dc = (int*)alloc((size_t)N * 4);           // in-degree by col (CSR counts)
    int* startv = (int*)alloc((size_t)N * 4);
    int* cursor = (int*)alloc((size_t)N * 4);
    int* partial = (int*)alloc((size_t)N * 4);
    int* blockSum = (int*)alloc(1024 * 4);
    int* blockOff = (int*)alloc(1024 * 4);
    float2* pseudo = (float2*)alloc((size_t)E * 8);
    float2* pseudoPerm = (float2*)alloc((size_t)E * 8);
    int* rowPerm = (int*)alloc((size_t)E * 4);
    float4* gauss = (float4*)alloc((size_t)E * 16);
    float* h = (float*)alloc((size_t)N * 64 * 4);
    float* m = (float*)alloc((size_t)N * KAUG * 4);
    float* agg = (float*)alloc((size_t)N * 64 * 4);
    float* W2 = (float*)alloc((size_t)KAUG * 64 * 4);
    float* sums = (float*)alloc(2 * 64 * 4);
    (void)ws_size; // ~95 MB

    hipMemsetAsync(dr, 0, (size_t)N * 4, stream);
    hipMemsetAsync(dc, 0, (size_t)N * 4, stream);
    degree_kernel<<<2048, 256, 0, stream>>>(rowi, coli, dr, dc, E);
    pseudo_kernel<<<2048, 256, 0, stream>>>(rowi, coli, dr, dc, pseudo, E);

    const int scanB = (N + 255) / 256;  // 196 for N=50000 (must be <= 1024)
    scan_phase1<<<scanB, 256, 0, stream>>>(dc, partial, blockSum, N);
    scan_phase2<<<1, 1024, 0, stream>>>(blockSum, blockOff, scanB);
    scan_phase3<<<scanB, 256, 0, stream>>>(partial, blockOff, startv, cursor, N);

    csr_scatter<<<2048, 256, 0, stream>>>(rowi, coli, pseudo, cursor, rowPerm, pseudoPerm, E);

    // h = feature @ emb_w + emb_b   [N,128]x[128,64]
    gemm_bias<128, 64, 32><<<(N + 31) / 32, 256, 0, stream>>>(feature, emb_w, emb_b, h, N);

    const int pullBlocks = (N + 3) / 4;
    for (int i = 0; i < 3; ++i) {
        gauss_kernel<<<1024, 256, 0, stream>>>(pseudoPerm, pp_w + i * 4, pp_b + i * 2,
                                               mu + i * 6, isg + i * 6, gauss, E);
        w2_transform<<<(KAUG * 64 + 255) / 256, 256, 0, stream>>>(
            fc_w + (size_t)i * 64 * 192, fc_b + (size_t)i * 192, W2, 64);
        pull_kernel<<<pullBlocks, 256, 0, stream>>>(startv, dc, rowPerm, gauss, h, m, N);
        // no agg memset: gemm_bias fully overwrites agg before any read
        gemm_bias<KAUG, 64, 16><<<(N + 15) / 16, 256, 0, stream>>>(m, W2, nullptr, agg, N);
        hipMemsetAsync(sums, 0, 2 * 64 * 4, stream);
        bn_stats<64><<<256, 256, 0, stream>>>(agg, N, sums);
        bn_apply<64, true><<<2048, 256, 0, stream>>>(agg, sums, bn_g + i * 64, bn_b + i * 64,
                                                     h, h, N);
    }

    // last layer: 16 classes, no residual, write d_out (f32)
    gauss_kernel<<<1024, 256, 0, stream>>>(pseudoPerm, pp_w_l, pp_b_l, mu_l, isg_l, gauss, E);
    w2_transform<<<(KAUG * 16 + 255) / 256, 256, 0, stream>>>(fc_w_l, fc_b_l, W2, 16);
    pull_kernel<<<pullBlocks, 256, 0, stream>>>(startv, dc, rowPerm, gauss, h, m, N);
    gemm_bias<KAUG, 16, 32><<<(N + 31) / 32, 256, 0, stream>>>(m, W2, nullptr, agg, N);
    hipMemsetAsync(sums, 0, 2 * 16 * 4, stream);
    bn_stats<16><<<256, 256, 0, stream>>>(agg, N, sums);
    bn_apply<16, false><<<2048, 256, 0, stream>>>(agg, sums, bn_g_l, bn_b_l, nullptr,
                                                  (float*)d_out, N);
}

// Round 11
// 703.515 us; speedup vs baseline: 3.8823x; 1.1168x over previous
//
#include <hip/hip_runtime.h>
#include <cstdint>
#include <cstddef>

// MoNet (GMM graph conv) forward, MI355X — round 11 (= round-10 resubmit, unbenched).
// r9 measured 786 us: top = csr_scatter 66us (78MB scattered writes) + degree 66us (atomic floor).
// This round: fuse pseudo into scatter (one 16B record/edge), fuse gauss into pull
// (lane-parallel LDS staging), fold sums-zeroing into w2_transform.

#define EPS 1e-5f
#define KAUG 196  // 192 m-columns + 3 gauss-sum columns + 1 zero pad

// ---------------- degree ----------------
__global__ void degree_kernel(const int* __restrict__ rowi, const int* __restrict__ coli,
                              int* __restrict__ dr, int* __restrict__ dc, int E) {
    int i = blockIdx.x * blockDim.x + threadIdx.x;
    int stride = gridDim.x * blockDim.x;
    for (; i < E; i += stride) {
        atomicAdd(&dr[rowi[i]], 1);
        atomicAdd(&dc[coli[i]], 1);
    }
}

// ---------------- hierarchical exclusive scan (3 phases) ----------------
__global__ __launch_bounds__(256) void scan_phase1(const int* __restrict__ cnt,
                                                   int* __restrict__ partial,
                                                   int* __restrict__ blockSum, int Nn) {
    __shared__ int sm[256];
    int tid = blockIdx.x * 256 + threadIdx.x;
    int v = (tid < Nn) ? cnt[tid] : 0;
    sm[threadIdx.x] = v;
    __syncthreads();
    for (int d = 1; d < 256; d <<= 1) {
        int t = (threadIdx.x >= d) ? sm[threadIdx.x - d] : 0;
        __syncthreads();
        sm[threadIdx.x] += t;
        __syncthreads();
    }
    if (tid < Nn) partial[tid] = sm[threadIdx.x] - v;  // exclusive within block
    if (threadIdx.x == 255) blockSum[blockIdx.x] = sm[255];
}

__global__ __launch_bounds__(1024) void scan_phase2(const int* __restrict__ blockSum,
                                                    int* __restrict__ blockOff, int B) {
    __shared__ int sm[1024];
    int v = (threadIdx.x < B) ? blockSum[threadIdx.x] : 0;
    sm[threadIdx.x] = v;
    __syncthreads();
    for (int d = 1; d < 1024; d <<= 1) {
        int t = (threadIdx.x >= d) ? sm[threadIdx.x - d] : 0;
        __syncthreads();
        sm[threadIdx.x] += t;
        __syncthreads();
    }
    if (threadIdx.x < B) blockOff[threadIdx.x] = sm[threadIdx.x] - v;  // exclusive
}

__global__ __launch_bounds__(256) void scan_phase3(const int* __restrict__ partial,
                                                   const int* __restrict__ blockOff,
                                                   int* __restrict__ start,
                                                   int* __restrict__ cursor, int Nn) {
    int tid = blockIdx.x * 256 + threadIdx.x;
    if (tid < Nn) {
        int s = partial[tid] + blockOff[blockIdx.x];
        start[tid] = s;
        cursor[tid] = s;
    }
}

// ---------------- fused scatter: degree->pseudo + counting-sort into 16B records ----------------
// perm[pos] = {rowbits, srcs=rsqrt(dr[r]+1), dsts=rsqrt(dc[d]+1), 0}
__global__ void csr_scatter(const int* __restrict__ rowi, const int* __restrict__ coli,
                            const int* __restrict__ dr, const int* __restrict__ dc,
                            int* __restrict__ cursor, float4* __restrict__ perm, int E) {
    int i = blockIdx.x * blockDim.x + threadIdx.x;
    int stride = gridDim.x * blockDim.x;
    for (; i < E; i += stride) {
        int r = rowi[i];
        int d = coli[i];
        int pos = atomicAdd(&cursor[d], 1);
        float a = rsqrtf((float)dr[r] + 1.0f);
        float b = rsqrtf((float)dc[d] + 1.0f);
        perm[pos] = make_float4(__int_as_float(r), a, b, 0.0f);
    }
}

// ---------------- W2 transform (+ zero sums): W2[(k*64+j), c] = fc_w[j, k*C + c] ----------------
// W2 is [KAUG, C]: rows 0..191 weights, 192..194 = fc_b[k*C+c], 195 = 0
__global__ void w2_transform(const float* __restrict__ fcw, const float* __restrict__ fcb,
                             float* __restrict__ W2, float* __restrict__ sums, int C) {
    int i = blockIdx.x * blockDim.x + threadIdx.x;
    if (i < 128) sums[i] = 0.0f;  // folded bn_stats accumulator zeroing
    int tot = KAUG * C;
    if (i >= tot) return;
    int r = i / C, c = i - r * C;
    float v;
    if (r < 192) {
        int k = r >> 6, j = r & 63;
        v = fcw[j * (3 * C) + k * C + c];
    } else if (r < 195) {
        v = fcb[(r - 192) * C + c];
    } else {
        v = 0.0f;
    }
    W2[i] = v;
}

// ---------------- CSR pull with inline gauss: one wave per dst node ----------------
// Per 64-edge batch: lane j computes gauss for edge base+j from the 16B record
// (2 tanh + 3 exp) -> wave-private LDS; then all lanes gather h and accumulate.
// m[d, k*64+lane] = sum_e g_k(e) * h[row(e), lane]; m[d,192+k] = sum_e g_k
__global__ __launch_bounds__(256) void pull_kernel(const int* __restrict__ start,
                                                   const int* __restrict__ cnt,
                                                   const float4* __restrict__ perm,
                                                   const float* __restrict__ ppw,  // [2,2]
                                                   const float* __restrict__ ppb,  // [2]
                                                   const float* __restrict__ mu,   // [3,2]
                                                   const float* __restrict__ isg,  // [3,2]
                                                   const float* __restrict__ h,
                                                   float* __restrict__ m, int Nn) {
    __shared__ float4 gl[4][64];  // per-wave slice; wave-coherent, no block barrier
    int wv = threadIdx.x >> 6;
    int lane = threadIdx.x & 63;
    int d = blockIdx.x * 4 + wv;
    if (d >= Nn) return;
    float w00 = ppw[0], w01 = ppw[1], w10 = ppw[2], w11 = ppw[3];
    float b0 = ppb[0], b1 = ppb[1];
    float m00 = mu[0], m01 = mu[1], m10 = mu[2], m11 = mu[3], m20 = mu[4], m21 = mu[5];
    float s00 = isg[0], s01 = isg[1], s10 = isg[2], s11 = isg[3], s20 = isg[4], s21 = isg[5];

    int s = start[d];
    int e = s + cnt[d];
    float a0 = 0.0f, a1 = 0.0f, a2 = 0.0f;
    float g0s = 0.0f, g1s = 0.0f, g2s = 0.0f;
    const float* hl = h + lane;

    for (int base = s; base < e; base += 64) {
        int idx = base + lane;
        float4 rec = make_float4(0.0f, 0.0f, 0.0f, 0.0f);
        if (idx < e) rec = perm[idx];
        // gauss for this edge (lane-parallel); invalid lanes compute on zeros (unread)
        float ps0 = tanhf(fmaf(rec.z, w10, fmaf(rec.y, w00, b0)));
        float ps1 = tanhf(fmaf(rec.z, w11, fmaf(rec.y, w01, b1)));
        float d0, d1;
        d0 = (ps0 - m00) * s00; d1 = (ps1 - m01) * s01;
        float g0 = expf(-0.5f * (d0 * d0 + d1 * d1));
        d0 = (ps0 - m10) * s10; d1 = (ps1 - m11) * s11;
        float g1 = expf(-0.5f * (d0 * d0 + d1 * d1));
        d0 = (ps0 - m20) * s20; d1 = (ps1 - m21) * s21;
        float g2 = expf(-0.5f * (d0 * d0 + d1 * d1));
        gl[wv][lane] = make_float4(g0, g1, g2, rec.x);  // rec.x = row bits

        int cb = e - base;
        if (cb > 64) cb = 64;
        int j = 0;
        for (; j + 3 < cb; j += 4) {
            float4 q0 = gl[wv][j], q1 = gl[wv][j + 1], q2 = gl[wv][j + 2], q3 = gl[wv][j + 3];
            int r0 = __float_as_int(q0.w), r1 = __float_as_int(q1.w);
            int r2 = __float_as_int(q2.w), r3 = __float_as_int(q3.w);
            float h0 = hl[(size_t)r0 * 64], h1 = hl[(size_t)r1 * 64];
            float h2 = hl[(size_t)r2 * 64], h3 = hl[(size_t)r3 * 64];
            a0 = fmaf(q0.x, h0, a0); a1 = fmaf(q0.y, h0, a1); a2 = fmaf(q0.z, h0, a2);
            a0 = fmaf(q1.x, h1, a0); a1 = fmaf(q1.y, h1, a1); a2 = fmaf(q1.z, h1, a2);
            a0 = fmaf(q2.x, h2, a0); a1 = fmaf(q2.y, h2, a1); a2 = fmaf(q2.z, h2, a2);
            a0 = fmaf(q3.x, h3, a0); a1 = fmaf(q3.y, h3, a1); a2 = fmaf(q3.z, h3, a2);
            g0s += q0.x + q1.x + q2.x + q3.x;
            g1s += q0.y + q1.y + q2.y + q3.y;
            g2s += q0.z + q1.z + q2.z + q3.z;
        }
        for (; j < cb; ++j) {
            float4 q0 = gl[wv][j];
            int r0 = __float_as_int(q0.w);
            float h0 = hl[(size_t)r0 * 64];
            a0 = fmaf(q0.x, h0, a0); a1 = fmaf(q0.y, h0, a1); a2 = fmaf(q0.z, h0, a2);
            g0s += q0.x; g1s += q0.y; g2s += q0.z;
        }
    }
    float* mr = m + (size_t)d * KAUG;
    mr[lane] = a0;
    mr[64 + lane] = a1;
    mr[128 + lane] = a2;
    if (lane < 3) mr[192 + lane] = (lane == 0) ? g0s : ((lane == 1) ? g1s : g2s);
    if (lane == 3) mr[195] = 0.0f;
}

// ---------------- GEMM: Y[M,NC] = X[M,KDIM] @ W[KDIM,NC] (+ b if Bv) ----------------
template <int KDIM, int NC, int ROWS>
__global__ __launch_bounds__(256) void gemm_bias(const float* __restrict__ X,
                                                 const float* __restrict__ W,
                                                 const float* __restrict__ Bv,
                                                 float* __restrict__ Y, int M) {
    constexpr int TPR = 256 / ROWS;  // threads per row
    constexpr int CPT = NC / TPR;    // cols per thread (contiguous)
    __shared__ __align__(16) float Ws[KDIM * NC];
    __shared__ float Bs[NC];
    __shared__ float Xs[ROWS][KDIM + 1];

    for (int i = threadIdx.x; i < KDIM * NC; i += 256) Ws[i] = W[i];
    if (Bv && threadIdx.x < NC) Bs[threadIdx.x] = Bv[threadIdx.x];
    int row0 = blockIdx.x * ROWS;
    for (int i = threadIdx.x; i < ROWS * KDIM; i += 256) {
        int r = i / KDIM, k = i - r * KDIM;
        int gr = row0 + r;
        Xs[r][k] = (gr < M) ? X[(size_t)gr * KDIM + k] : 0.0f;
    }
    __syncthreads();

    int r = threadIdx.x / TPR;
    int lc = threadIdx.x % TPR;
    int gr = row0 + r;
    if (gr >= M) return;

    float acc[CPT];
#pragma unroll
    for (int j = 0; j < CPT; ++j) acc[j] = Bv ? Bs[lc * CPT + j] : 0.0f;
    for (int k = 0; k < KDIM; ++k) {
        float xv = Xs[r][k];
        const float* wr = &Ws[k * NC + lc * CPT];
#pragma unroll
        for (int j = 0; j < CPT; ++j) acc[j] = fmaf(xv, wr[j], acc[j]);
    }
    float* yr = Y + (size_t)gr * NC + lc * CPT;
#pragma unroll
    for (int j = 0; j < CPT; ++j) yr[j] = acc[j];
}

// ---------------- BN stats: per-channel sum & sumsq ----------------
template <int C>
__global__ __launch_bounds__(256) void bn_stats(const float* __restrict__ x, int Nn,
                                                float* __restrict__ sums) {
    constexpr int G = 256 / C;
    int c = threadIdx.x % C;
    int g = threadIdx.x / C;
    float s = 0.0f, ss = 0.0f;
    int totalG = gridDim.x * G;
    for (int r = blockIdx.x * G + g; r < Nn; r += totalG) {
        float v = x[(size_t)r * C + c];
        s += v;
        ss += v * v;
    }
    __shared__ float ls[256], lss[256];
    ls[threadIdx.x] = s;
    lss[threadIdx.x] = ss;
    __syncthreads();
    if (threadIdx.x < C) {
        float ts = 0.0f, tss = 0.0f;
#pragma unroll
        for (int gg = 0; gg < G; ++gg) {
            ts += ls[gg * C + threadIdx.x];
            tss += lss[gg * C + threadIdx.x];
        }
        atomicAdd(&sums[threadIdx.x], ts);
        atomicAdd(&sums[C + threadIdx.x], tss);
    }
}

// ---------------- BN apply + relu (+ residual) ----------------
template <int C, bool RES>
__global__ __launch_bounds__(256) void bn_apply(const float* __restrict__ agg,
                                                const float* __restrict__ sums,
                                                const float* __restrict__ gam,
                                                const float* __restrict__ bet,
                                                const float* __restrict__ hin,
                                                float* __restrict__ hout, int Nn) {
    size_t i = (size_t)blockIdx.x * blockDim.x + threadIdx.x;
    size_t tot = (size_t)Nn * C;
    size_t stride = (size_t)gridDim.x * blockDim.x;
    float invN = 1.0f / (float)Nn;
    for (; i < tot; i += stride) {
        int c = (int)(i & (C - 1));
        float mean = sums[c] * invN;
        float var = sums[C + c] * invN - mean * mean;
        float scale = gam[c] * rsqrtf(var + EPS);
        float v = (agg[i] - mean) * scale + bet[c];
        v = fmaxf(v, 0.0f);
        if (RES) v += hin[i];
        hout[i] = v;
    }
}

extern "C" void kernel_launch(void* const* d_in, const int* in_sizes, int n_in,
                              void* d_out, int out_size, void* d_ws, size_t ws_size,
                              hipStream_t stream) {
    const float* feature = (const float*)d_in[0];
    const float* emb_w = (const float*)d_in[1];
    const float* emb_b = (const float*)d_in[2];
    const float* fc_w = (const float*)d_in[3];    // [3,64,192]
    const float* fc_b = (const float*)d_in[4];    // [3,192]
    const float* mu = (const float*)d_in[5];      // [3,3,2]
    const float* isg = (const float*)d_in[6];     // [3,3,2]
    const float* pp_w = (const float*)d_in[7];    // [3,2,2]
    const float* pp_b = (const float*)d_in[8];    // [3,2]
    const float* bn_g = (const float*)d_in[9];    // [3,64]
    const float* bn_b = (const float*)d_in[10];   // [3,64]
    const float* fc_w_l = (const float*)d_in[11]; // [64,48]
    const float* fc_b_l = (const float*)d_in[12]; // [48]
    const float* mu_l = (const float*)d_in[13];   // [3,2]
    const float* isg_l = (const float*)d_in[14];  // [3,2]
    const float* pp_w_l = (const float*)d_in[15]; // [2,2]
    const float* pp_b_l = (const float*)d_in[16]; // [2]
    const float* bn_g_l = (const float*)d_in[17]; // [16]
    const float* bn_b_l = (const float*)d_in[18]; // [16]
    const int* edge = (const int*)d_in[19];       // [2,E] int32

    const int N = in_sizes[0] / 128;
    const int E = in_sizes[19] / 2;
    const int* rowi = edge;
    const int* coli = edge + E;

    char* ws = (char*)d_ws;
    size_t off = 0;
    auto alloc = [&](size_t sz) -> void* {
        void* p = ws + off;
        off += (sz + 255) & ~(size_t)255;
        return p;
    };
    int* dr = (int*)alloc((size_t)N * 4);
    int* dc = (int*)alloc((size_t)N * 4);           // in-degree by col (CSR counts)
    int* startv = (int*)alloc((size_t)N * 4);
    int* cursor = (int*)alloc((size_t)N * 4);
    int* partial = (int*)alloc((size_t)N * 4);
    int* blockSum = (int*)alloc(1024 * 4);
    int* blockOff = (int*)alloc(1024 * 4);
    float4* perm = (float4*)alloc((size_t)E * 16); // {rowbits, srcs, dsts, 0} per edge
    float* h = (float*)alloc((size_t)N * 64 * 4);
    float* m = (float*)alloc((size_t)N * KAUG * 4);
    float* agg = (float*)alloc((size_t)N * 64 * 4);
    float* W2 = (float*)alloc((size_t)KAUG * 64 * 4);
    float* sums = (float*)alloc(2 * 64 * 4);
    (void)ws_size; // ~75 MB

    hipMemsetAsync(dr, 0, (size_t)N * 4, stream);
    hipMemsetAsync(dc, 0, (size_t)N * 4, stream);
    degree_kernel<<<2048, 256, 0, stream>>>(rowi, coli, dr, dc, E);

    const int scanB = (N + 255) / 256;  // 196 for N=50000 (must be <= 1024)
    scan_phase1<<<scanB, 256, 0, stream>>>(dc, partial, blockSum, N);
    scan_phase2<<<1, 1024, 0, stream>>>(blockSum, blockOff, scanB);
    scan_phase3<<<scanB, 256, 0, stream>>>(partial, blockOff, startv, cursor, N);

    csr_scatter<<<2048, 256, 0, stream>>>(rowi, coli, dr, dc, cursor, perm, E);

    // h = feature @ emb_w + emb_b   [N,128]x[128,64]
    gemm_bias<128, 64, 32><<<(N + 31) / 32, 256, 0, stream>>>(feature, emb_w, emb_b, h, N);

    const int pullBlocks = (N + 3) / 4;
    for (int i = 0; i < 3; ++i) {
        w2_transform<<<(KAUG * 64 + 255) / 256, 256, 0, stream>>>(
            fc_w + (size_t)i * 64 * 192, fc_b + (size_t)i * 192, W2, sums, 64);
        pull_kernel<<<pullBlocks, 256, 0, stream>>>(startv, dc, perm,
                                                    pp_w + i * 4, pp_b + i * 2,
                                                    mu + i * 6, isg + i * 6, h, m, N);
        gemm_bias<KAUG, 64, 16><<<(N + 15) / 16, 256, 0, stream>>>(m, W2, nullptr, agg, N);
        bn_stats<64><<<256, 256, 0, stream>>>(agg, N, sums);
        bn_apply<64, true><<<2048, 256, 0, stream>>>(agg, sums, bn_g + i * 64, bn_b + i * 64,
                                                     h, h, N);
    }

    // last layer: 16 classes, no residual, write d_out (f32)
    w2_transform<<<(KAUG * 16 + 255) / 256, 256, 0, stream>>>(fc_w_l, fc_b_l, W2, sums, 16);
    pull_kernel<<<pullBlocks, 256, 0, stream>>>(startv, dc, perm,
                                                pp_w_l, pp_b_l, mu_l, isg_l, h, m, N);
    gemm_bias<KAUG, 16, 32><<<(N + 31) / 32, 256, 0, stream>>>(m, W2, nullptr, agg, N);
    bn_stats<16><<<256, 256, 0, stream>>>(agg, N, sums);
    bn_apply<16, false><<<2048, 256, 0, stream>>>(agg, sums, bn_g_l, bn_b_l, nullptr,
                                                  (float*)d_out, N);
}